// Round 7
// baseline (221.443 us; speedup 1.0000x reference)
//
#include <hip/hip_runtime.h>
#include <stdint.h>

// ---------------------------------------------------------------------------
// AbstractAttention  B=2,S=2048,H=16,Dh=64,Dm=1024. fp32 in/out, bf16 MFMA.
// R13: fuse the X fp32->bf16 conversion into the QKV GEMM's A-staging.
// R12 post-mortem: conv/QKV/final each <50.6us (never in top-5), three GEMM
// shape experiments all neutral -> the non-attn 168us is spread across
// sequential memory passes + drain bubbles, not one inner loop. So remove a
// stage: QKV GEMM reg-stages A from fp32 X (float4 x2 -> f2b RNE -> ds_write
// b128, identical swizzled LDS image -> bit-exact outputs), next-tile loads
// issued before the barrier to hide under the B global_load_lds drain.
// convall shrinks to weights-only (1024 blocks). attn (R6 verbatim) and
// final GEMM (R12 64x64) unchanged.
// ---------------------------------------------------------------------------

typedef __attribute__((ext_vector_type(8))) short short8;
typedef __attribute__((ext_vector_type(4))) short short4v;
typedef __attribute__((ext_vector_type(4))) float floatx4;
typedef __attribute__((ext_vector_type(4))) unsigned int uintx4;
typedef __attribute__((ext_vector_type(2))) unsigned int uint2v;

#define MFMA16(a, b, c) __builtin_amdgcn_mfma_f32_16x16x32_bf16(a, b, c, 0, 0, 0)

#if __has_builtin(__builtin_amdgcn_mfma_f32_16x16x16bf16_1k)
#define HAVE_K16 1
#define MFMAK16(a, b, c) __builtin_amdgcn_mfma_f32_16x16x16bf16_1k(a, b, c, 0, 0, 0)
#else
#define HAVE_K16 0
#endif

__device__ __forceinline__ unsigned short f2b(float f) {  // RNE fp32->bf16
  unsigned int u = __builtin_bit_cast(unsigned int, f);
  u = (u + 0x7fffu + ((u >> 16) & 1u)) >> 16;
  return (unsigned short)u;
}
__device__ __forceinline__ unsigned int packf2b(float lo, float hi) {
  return (unsigned int)f2b(lo) | ((unsigned int)f2b(hi) << 16);
}
__device__ __forceinline__ float exp2f_fast(float x) {
#if __has_builtin(__builtin_amdgcn_exp2f)
  return __builtin_amdgcn_exp2f(x);
#else
  return exp2f(x);
#endif
}
__device__ __forceinline__ unsigned int pack2_bf16(float lo, float hi) {
#if __has_builtin(__builtin_amdgcn_perm)
  return __builtin_amdgcn_perm(__builtin_bit_cast(unsigned int, hi),
                               __builtin_bit_cast(unsigned int, lo), 0x07060302u);
#else
  return (__builtin_bit_cast(unsigned int, lo) >> 16) |
         (__builtin_bit_cast(unsigned int, hi) & 0xffff0000u);
#endif
}

__device__ __forceinline__ void async_copy16(void* lds, const void* g) {
  __builtin_amdgcn_global_load_lds(
      (const __attribute__((address_space(1))) unsigned int*)g,
      (__attribute__((address_space(3))) unsigned int*)lds, 16, 0, 0);
}

// 4x4 transpose across lanes within col&3 groups (2 butterfly rounds).
__device__ __forceinline__ void xpose4(floatx4& v, int lane) {
  {
    float s0 = __shfl_xor(v[1], 1, 64);
    float s1 = __shfl_xor(v[0], 1, 64);
    float s2 = __shfl_xor(v[3], 1, 64);
    float s3 = __shfl_xor(v[2], 1, 64);
    if (lane & 1) { v[0] = s0; v[2] = s2; } else { v[1] = s1; v[3] = s3; }
  }
  {
    float s0 = __shfl_xor(v[2], 2, 64);
    float s1 = __shfl_xor(v[3], 2, 64);
    float s2 = __shfl_xor(v[0], 2, 64);
    float s3 = __shfl_xor(v[1], 2, 64);
    if (lane & 2) { v[0] = s0; v[1] = s1; } else { v[2] = s2; v[3] = s3; }
  }
}

// ---------------------------------------------------------------------------
// Weight conversions only (X conversion fused into the QKV GEMM).
// blocks [0,768): W_{Q,K,V} [h,d,e] -> [n=h*64+e][k=d]
// blocks [768,1024): W_O [he,d] -> [n=d][k=he]
// ---------------------------------------------------------------------------
__global__ __launch_bounds__(256) void convw(
    const float* __restrict__ WQ, const float* __restrict__ WK,
    const float* __restrict__ WV, const float* __restrict__ WO,
    unsigned short* __restrict__ wout, unsigned short* __restrict__ woout) {
  __shared__ float T[64][65];
  const int bid = blockIdx.x;
  const int t = threadIdx.x;
  const int rr = t >> 4, cc = t & 15;
  if (bid < 768) {
    const int yy = bid >> 8, x = bid & 255;
    const float* in = (yy == 0) ? WQ : ((yy == 1) ? WK : WV);
    const int h = x >> 4, d0 = (x & 15) << 6;
#pragma unroll
    for (int it = 0; it < 4; ++it) {
      int dl = it * 16 + rr;
      float4 v = *(const float4*)&in[(size_t)h * 65536 + (size_t)(d0 + dl) * 64 + cc * 4];
      T[dl][cc * 4 + 0] = v.x; T[dl][cc * 4 + 1] = v.y;
      T[dl][cc * 4 + 2] = v.z; T[dl][cc * 4 + 3] = v.w;
    }
    __syncthreads();
    unsigned short* ob = wout + (size_t)yy * 1048576;
#pragma unroll
    for (int it = 0; it < 4; ++it) {
      int e = it * 16 + rr;
      ushort4 u;
      u.x = f2b(T[cc * 4 + 0][e]); u.y = f2b(T[cc * 4 + 1][e]);
      u.z = f2b(T[cc * 4 + 2][e]); u.w = f2b(T[cc * 4 + 3][e]);
      *(ushort4*)&ob[(size_t)(h * 64 + e) * 1024 + d0 + cc * 4] = u;
    }
    return;
  }
  {
    const int x = bid - 768;
    const int r0 = (x & 15) << 6, c0 = (x >> 4) << 6;
#pragma unroll
    for (int it = 0; it < 4; ++it) {
      int rl = it * 16 + rr;
      float4 v = *(const float4*)&WO[(size_t)(r0 + rl) * 1024 + c0 + cc * 4];
      T[rl][cc * 4 + 0] = v.x; T[rl][cc * 4 + 1] = v.y;
      T[rl][cc * 4 + 2] = v.z; T[rl][cc * 4 + 3] = v.w;
    }
    __syncthreads();
#pragma unroll
    for (int it = 0; it < 4; ++it) {
      int dl = it * 16 + rr;
      ushort4 u;
      u.x = f2b(T[cc * 4 + 0][dl]); u.y = f2b(T[cc * 4 + 1][dl]);
      u.z = f2b(T[cc * 4 + 2][dl]); u.w = f2b(T[cc * 4 + 3][dl]);
      *(ushort4*)&woout[(size_t)(c0 + dl) * 1024 + r0 + cc * 4] = u;
    }
  }
}

// ---------------------------------------------------------------------------
// GEMM, 8 waves / 512 threads, TM x TN tile, BK=64, 2-barrier loop.
// TM=128,TN=128: waves 4(m) x 2(n), wave tile 32x64 (MI=2,NJ=4). LDS 32KB.
// TM=64, TN=64 : waves 2(m) x 4(n), wave tile 32x16 (MI=2,NJ=1). LDS 16KB.
// CONVA=1 (requires TM=128): A is fp32; reg-stage (2x float4 -> f2b RNE ->
// ds_write b128) into the IDENTICAL swizzled LDS image the gload_lds path
// produces: LDS[r][pos] = global[r][pos^(r&7)]. Next-tile loads issued
// before the barrier so latency hides under the B gload_lds drain.
// Fragment read: block (kk*4+quad)^(col&7).
// NZ=3: z=0 q (mode1, qscale), z=1 k (mode1), z=2 v (mode2 [b,h,e,s]).
// NZ=1: fp32 [m][n] + bias (mode 0).
// ---------------------------------------------------------------------------
template <int TM, int TN, int NZ, int CONVA>
__global__ __launch_bounds__(512, (TM == 128) ? 6 : 4) void gemm512(
    const short* __restrict__ A0, const short* __restrict__ A1,
    const short* __restrict__ A2, const short* __restrict__ B0,
    const short* __restrict__ B1, const short* __restrict__ B2,
    const float* __restrict__ bias0, const float* __restrict__ bias1,
    const float* __restrict__ bias2, unsigned short* __restrict__ ob0,
    unsigned short* __restrict__ ob1, unsigned short* __restrict__ ob2,
    float* __restrict__ outf, float qscale) {
  constexpr int WAVES_N = (TN == 128) ? 2 : 4;
  constexpr int NJ = TN / (WAVES_N * 16);
  constexpr int NY = 4096 / TM;
  __shared__ short As[TM * 64];
  __shared__ short Bs[TN * 64];

  const int L = blockIdx.x;
  const int x = L / (NY * NZ);
  const int r = L - x * (NY * NZ);
  const int y = r / NZ;
  const int z = r - y * NZ;

  const short* A = (z == 0) ? A0 : (z == 1) ? A1 : A2;
  const short* Bt = (z == 0) ? B0 : (z == 1) ? B1 : B2;

  const int tid = threadIdx.x;
  const int lane = tid & 63, w = tid >> 6;
  const int quad = lane >> 4, col = lane & 15;
  const int m0 = y * TM, n0 = x * TN;
  const int wm = (w / WAVES_N) * 32, wn = (w % WAVES_N) * (NJ * 16);

  floatx4 acc[2][NJ] = {};

  // Staging geometry: 8 rows per group (8 lanes x 16B = 128B row).
  const int slr = lane >> 3, sch = lane & 7;
  const int sgc = sch ^ slr;
  const short* ga = A + (size_t)(m0 + w * (TM / 8) + slr) * 1024 + sgc * 8;
  const short* gb = Bt + (size_t)(n0 + w * (TN / 8) + slr) * 1024 + sgc * 8;
  const int fsw = col & 7;

  // CONVA path state (fp32 A, 16 rows/wave in two 8-row groups).
  const float* gaf0 = nullptr;
  const float* gaf1 = nullptr;
  uintx4* awp0 = nullptr;
  uintx4* awp1 = nullptr;
  float4 a00, a01, a10, a11;
  if (CONVA) {
    const float* Af = (const float*)A;
    gaf0 = Af + (size_t)(m0 + w * 16 + slr) * 1024 + sgc * 8;
    gaf1 = gaf0 + 8 * 1024;
    awp0 = (uintx4*)&As[(w * 16 + slr) * 64 + sch * 8];
    awp1 = (uintx4*)&As[(w * 16 + 8 + slr) * 64 + sch * 8];
    a00 = *(const float4*)gaf0;
    a01 = *(const float4*)(gaf0 + 4);
    a10 = *(const float4*)gaf1;
    a11 = *(const float4*)(gaf1 + 4);
  }

  for (int k0 = 0; k0 < 1024; k0 += 64) {
    if (CONVA) {
      uintx4 p0, p1;
      p0.x = packf2b(a00.x, a00.y); p0.y = packf2b(a00.z, a00.w);
      p0.z = packf2b(a01.x, a01.y); p0.w = packf2b(a01.z, a01.w);
      p1.x = packf2b(a10.x, a10.y); p1.y = packf2b(a10.z, a10.w);
      p1.z = packf2b(a11.x, a11.y); p1.w = packf2b(a11.z, a11.w);
      *awp0 = p0;
      *awp1 = p1;
    } else {
      if (TM == 128) {
        async_copy16(&As[(w * 16) * 64], ga);
        async_copy16(&As[(w * 16 + 8) * 64], ga + 8 * 1024);
      } else {
        async_copy16(&As[(w * 8) * 64], ga);
      }
      ga += 64;
    }
    if (TN == 128) {
      async_copy16(&Bs[(w * 16) * 64], gb);
      async_copy16(&Bs[(w * 16 + 8) * 64], gb + 8 * 1024);
    } else {
      async_copy16(&Bs[(w * 8) * 64], gb);
    }
    gb += 64;
    if (CONVA && k0 < 960) {
      gaf0 += 64; gaf1 += 64;
      a00 = *(const float4*)gaf0;
      a01 = *(const float4*)(gaf0 + 4);
      a10 = *(const float4*)gaf1;
      a11 = *(const float4*)(gaf1 + 4);
    }
    __syncthreads();
#pragma unroll
    for (int kk = 0; kk < 2; ++kk) {
      short8 af[2], bf[NJ];
#pragma unroll
      for (int mi = 0; mi < 2; ++mi)
        af[mi] = *(const short8*)&As[(wm + mi * 16 + col) * 64 +
                                     (((kk * 4 + quad) ^ fsw) * 8)];
#pragma unroll
      for (int nj = 0; nj < NJ; ++nj)
        bf[nj] = *(const short8*)&Bs[(wn + nj * 16 + col) * 64 +
                                     (((kk * 4 + quad) ^ fsw) * 8)];
#pragma unroll
      for (int mi = 0; mi < 2; ++mi)
#pragma unroll
        for (int nj = 0; nj < NJ; ++nj)
          acc[mi][nj] = MFMA16(af[mi], bf[nj], acc[mi][nj]);
    }
    __syncthreads();
  }

  const float* bias = (z == 0) ? bias0 : (z == 1) ? bias1 : bias2;
  unsigned short* outb = (z == 0) ? ob0 : (z == 1) ? ob1 : ob2;
  const int mode = (NZ == 3) ? ((z == 2) ? 2 : 1) : 0;
  const float scale = (NZ == 3 && z == 0) ? qscale : 1.0f;

  float bv[NJ];
#pragma unroll
  for (int nj = 0; nj < NJ; ++nj) bv[nj] = bias[n0 + wn + nj * 16 + col];

  if (mode == 2) {
#pragma unroll
    for (int mi = 0; mi < 2; ++mi)
#pragma unroll
      for (int nj = 0; nj < NJ; ++nj) {
        int m = m0 + wm + mi * 16 + quad * 4;
        int n = n0 + wn + nj * 16 + col;
        int bb = m >> 11, s = m & 2047, h = n >> 6, e = n & 63;
        ushort4 u;
        u.x = f2b(acc[mi][nj][0] + bv[nj]);
        u.y = f2b(acc[mi][nj][1] + bv[nj]);
        u.z = f2b(acc[mi][nj][2] + bv[nj]);
        u.w = f2b(acc[mi][nj][3] + bv[nj]);
        *(ushort4*)&outb[(((size_t)bb * 16 + h) * 64 + e) * 2048 + s] = u;
      }
  } else {
#pragma unroll
    for (int mi = 0; mi < 2; ++mi)
#pragma unroll
      for (int nj = 0; nj < NJ; ++nj) {
        floatx4 v;
#pragma unroll
        for (int rr = 0; rr < 4; ++rr) v[rr] = (acc[mi][nj][rr] + bv[nj]) * scale;
        xpose4(v, lane);
        int m = m0 + wm + mi * 16 + quad * 4 + (col & 3);
        int nb = n0 + wn + nj * 16 + (col & ~3);
        if (mode == 0) {
          *(floatx4*)&outf[(size_t)m * 1024 + nb] = v;
        } else {
          int bb = m >> 11, s = m & 2047, h = nb >> 6, e = nb & 63;
          ushort4 u;
          u.x = f2b(v[0]); u.y = f2b(v[1]); u.z = f2b(v[2]); u.w = f2b(v[3]);
          *(ushort4*)&outb[(((size_t)bb * 16 + h) * 2048 + s) * 64 + e] = u;
        }
      }
  }
}

// ---------------------------------------------------------------------------
// Flash attention (causal), S^T formulation, 64 q/block, double-buffered K/V,
// PV via K=16 MFMA (P^T C-layout == 16x16x16 B-frag layout).  (R6, verbatim)
// ---------------------------------------------------------------------------
#if !HAVE_K16
__device__ __forceinline__ void exchange4(const unsigned int* u01,
                                          const unsigned int* u23, int srcA,
                                          int srcB, bool hiq, short8& pf0,
                                          short8& pf1) {
  unsigned int xA0 = (unsigned int)__shfl((int)u01[0], srcA, 64);
  unsigned int xA1 = (unsigned int)__shfl((int)u01[1], srcA, 64);
  unsigned int yA0 = (unsigned int)__shfl((int)u23[0], srcA, 64);
  unsigned int yA1 = (unsigned int)__shfl((int)u23[1], srcA, 64);
  unsigned int xB0 = (unsigned int)__shfl((int)u01[0], srcB, 64);
  unsigned int xB1 = (unsigned int)__shfl((int)u01[1], srcB, 64);
  unsigned int yB0 = (unsigned int)__shfl((int)u23[0], srcB, 64);
  unsigned int yB1 = (unsigned int)__shfl((int)u23[1], srcB, 64);
  uintx4 v0;
  v0.x = hiq ? xA1 : xA0; v0.y = hiq ? yA1 : yA0;
  v0.z = hiq ? xB1 : xB0; v0.w = hiq ? yB1 : yB0;
  pf0 = __builtin_bit_cast(short8, v0);
  xA0 = (unsigned int)__shfl((int)u01[2], srcA, 64);
  xA1 = (unsigned int)__shfl((int)u01[3], srcA, 64);
  yA0 = (unsigned int)__shfl((int)u23[2], srcA, 64);
  yA1 = (unsigned int)__shfl((int)u23[3], srcA, 64);
  xB0 = (unsigned int)__shfl((int)u01[2], srcB, 64);
  xB1 = (unsigned int)__shfl((int)u01[3], srcB, 64);
  yB0 = (unsigned int)__shfl((int)u23[2], srcB, 64);
  yB1 = (unsigned int)__shfl((int)u23[3], srcB, 64);
  uintx4 v1;
  v1.x = hiq ? xA1 : xA0; v1.y = hiq ? yA1 : yA0;
  v1.z = hiq ? xB1 : xB0; v1.w = hiq ? yB1 : yB0;
  pf1 = __builtin_bit_cast(short8, v1);
}
#endif

__device__ __forceinline__ void stage_kv(short* Kbuf, short* Vbuf,
                                         const short* kg, const short* vg,
                                         int kv0, int w, int slr, int sgc) {
  const short* kr = kg + (size_t)(kv0 + w * 16 + slr) * 64 + sgc * 8;
  async_copy16(&Kbuf[(w * 16) * 64], kr);
  async_copy16(&Kbuf[(w * 16 + 8) * 64], kr + 8 * 64);
  const short* vr = vg + (size_t)(w * 16 + slr) * 2048 + kv0 + sgc * 8;
  async_copy16(&Vbuf[(w * 16) * 64], vr);
  async_copy16(&Vbuf[(w * 16 + 8) * 64], vr + 8 * 2048);
}

__global__ __launch_bounds__(256) void attn(const short* __restrict__ q,
                                            const short* __restrict__ k,
                                            const short* __restrict__ vt,
                                            unsigned short* __restrict__ z) {
  __shared__ short Ks[2][64 * 64];
  __shared__ short Vs[2][64 * 64];

  const int tid = threadIdx.x;
  const int lane = tid & 63, w = tid >> 6;
  const int quad = lane >> 4, col = lane & 15;
  const int qt = 31 - (blockIdx.x >> 5), bh = blockIdx.x & 31;
  const int q0 = qt * 64, qw0 = q0 + w * 16;
  const size_t base = (size_t)bh * (2048 * 64);

  const short* qp = q + base + (size_t)(qw0 + col) * 64 + quad * 8;
  short8 bq0 = *(const short8*)qp;
  short8 bq1 = *(const short8*)(qp + 32);

  floatx4 o[4] = {};
  float m_run = -1e30f, l_run = 0.f;

  const short* kg = k + base;
  const short* vg = vt + base;
  const int ksw = col & 7;
  const int slr = lane >> 3, sgc = (lane & 7) ^ slr;
#if !HAVE_K16
  const int srcA = ((quad & 1) << 5) + col, srcB = srcA + 16;
  const bool hiq = (quad & 2) != 0;
#endif

  stage_kv(Ks[0], Vs[0], kg, vg, 0, w, slr, sgc);
  int p = 0;

  for (int t = 0; t <= qt; ++t) {
    __syncthreads();
    if (t < qt) stage_kv(Ks[p ^ 1], Vs[p ^ 1], kg, vg, (t + 1) * 64, w, slr, sgc);

    const bool diag = (t == qt);
    const int mtmax = diag ? w : 3;

    floatx4 st[4];
#pragma unroll
    for (int mt = 0; mt < 4; ++mt) {
      if (mt <= mtmax) {
        const short* kb = &Ks[p][(mt * 16 + col) * 64];
        short8 ka0 = *(const short8*)(kb + (quad ^ ksw) * 8);
        short8 ka1 = *(const short8*)(kb + ((quad + 4) ^ ksw) * 8);
        floatx4 a = {0.f, 0.f, 0.f, 0.f};
        a = MFMA16(ka0, bq0, a);
        a = MFMA16(ka1, bq1, a);
        if (diag && mt == mtmax) {
#pragma unroll
          for (int r = 0; r < 4; ++r)
            if (quad * 4 + r > col) a[r] = -1e9f;
        }
        st[mt] = a;
      }
    }

    float pmax = -3e38f;
#pragma unroll
    for (int mt = 0; mt < 4; ++mt)
      if (mt <= mtmax) {
#pragma unroll
        for (int r = 0; r < 4; ++r) pmax = fmaxf(pmax, st[mt][r]);
      }
    pmax = fmaxf(pmax, __shfl_xor(pmax, 16, 64));
    pmax = fmaxf(pmax, __shfl_xor(pmax, 32, 64));
    float mnew = fmaxf(m_run, pmax);
    float alpha = exp2f_fast(m_run - mnew);
    m_run = mnew;

    unsigned int u01[4], u23[4];
    float lsum = 0.f;
#pragma unroll
    for (int mt = 0; mt < 4; ++mt) {
      if (mt <= mtmax) {
        float p0 = exp2f_fast(st[mt][0] - mnew);
        float p1 = exp2f_fast(st[mt][1] - mnew);
        float p2 = exp2f_fast(st[mt][2] - mnew);
        float p3 = exp2f_fast(st[mt][3] - mnew);
        lsum += (p0 + p1) + (p2 + p3);
        u01[mt] = pack2_bf16(p0, p1);
        u23[mt] = pack2_bf16(p2, p3);
      } else {
        u01[mt] = 0u; u23[mt] = 0u;
      }
    }
    lsum += __shfl_xor(lsum, 16, 64);
    lsum += __shfl_xor(lsum, 32, 64);
    l_run = l_run * alpha + lsum;

#if HAVE_K16
    short4v pb[4];
#pragma unroll
    for (int mt = 0; mt < 4; ++mt) {
      uint2v uu;
      uu.x = u01[mt]; uu.y = u23[mt];
      pb[mt] = __builtin_bit_cast(short4v, uu);
    }
#pragma unroll
    for (int et = 0; et < 4; ++et) {
      const short* vrow = &Vs[p][(et * 16 + col) * 64];
      floatx4 t0 = o[et];
#pragma unroll
      for (int r = 0; r < 4; ++r) t0[r] *= alpha;
#pragma unroll
      for (int mt = 0; mt < 4; ++mt) {
        if (mt <= mtmax) {
          int c = mt * 2 + (quad >> 1);
          short4v va = *(const short4v*)&vrow[((c ^ ksw) * 8) + (quad & 1) * 4];
          t0 = MFMAK16(va, pb[mt], t0);
        }
      }
      o[et] = t0;
    }
#else
    short8 pf0, pf1;
    exchange4(u01, u23, srcA, srcB, hiq, pf0, pf1);
#pragma unroll
    for (int et = 0; et < 4; ++et) {
      const short* vb = &Vs[p][(et * 16 + col) * 64];
      short8 va0 = *(const short8*)(vb + (quad ^ ksw) * 8);
      short8 va1 = *(const short8*)(vb + ((quad + 4) ^ ksw) * 8);
      floatx4 t0 = o[et];
#pragma unroll
      for (int r = 0; r < 4; ++r) t0[r] *= alpha;
      t0 = MFMA16(va0, pf0, t0);
      t0 = MFMA16(va1, pf1, t0);
      o[et] = t0;
    }
#endif
    p ^= 1;
  }

  const int b = bh >> 4, h = bh & 15;
#if __has_builtin(__builtin_amdgcn_rcpf)
  const float invl = __builtin_amdgcn_rcpf(l_run);
#else
  const float invl = 1.f / l_run;
#endif
  unsigned short* zr = z + (((size_t)b * 2048 + qw0 + col) * 16 + h) * 64;
#pragma unroll
  for (int et = 0; et < 4; ++et) {
    ushort4 u;
    u.x = f2b(o[et][0] * invl); u.y = f2b(o[et][1] * invl);
    u.z = f2b(o[et][2] * invl); u.w = f2b(o[et][3] * invl);
    *(ushort4*)&zr[et * 16 + quad * 4] = u;
  }
}

// ---------------------------------------------------------------------------
extern "C" void kernel_launch(void* const* d_in, const int* in_sizes, int n_in,
                              void* d_out, int out_size, void* d_ws, size_t ws_size,
                              hipStream_t stream) {
  (void)in_sizes; (void)n_in; (void)out_size; (void)ws_size;
  const float* Xq = (const float*)d_in[0];
  const float* Xk = (const float*)d_in[1];
  const float* Xv = (const float*)d_in[2];
  const float* WQ = (const float*)d_in[3];
  const float* WK = (const float*)d_in[4];
  const float* WV = (const float*)d_in[5];
  const float* WO = (const float*)d_in[6];
  const float* bQ = (const float*)d_in[7];
  const float* bK = (const float*)d_in[8];
  const float* bV = (const float*)d_in[9];
  const float* bO = (const float*)d_in[10];
  float* out = (float*)d_out;

  unsigned short* wqt = (unsigned short*)d_ws;
  unsigned short* wkt = wqt + 1048576;
  unsigned short* wvt = wkt + 1048576;
  unsigned short* wot = wvt + 1048576;
  unsigned short* qb = wot + 1048576;
  unsigned short* kb = qb + 4194304;
  unsigned short* vtb = kb + 4194304;
  unsigned short* zb = vtb + 4194304;

  convw<<<1024, 256, 0, stream>>>(WQ, WK, WV, WO, wqt, wot);

  const float qscale = 0.125f * 1.44269504088896f;  // 1/sqrt(64) * log2(e)
  gemm512<128, 128, 3, 1><<<768, 512, 0, stream>>>(
      (const short*)Xq, (const short*)Xk, (const short*)Xv,
      (const short*)wqt, (const short*)wkt, (const short*)wvt, bQ, bK, bV, qb,
      kb, vtb, nullptr, qscale);

  attn<<<1024, 256, 0, stream>>>((const short*)qb, (const short*)kb,
                                 (const short*)vtb, zb);

  gemm512<64, 64, 1, 0><<<1024, 512, 0, stream>>>(
      (const short*)zb, (const short*)zb, (const short*)zb, (const short*)wot,
      (const short*)wot, (const short*)wot, bO, bO, bO, nullptr, nullptr,
      nullptr, out, 1.0f);
}

// Round 9
// 221.148 us; speedup vs baseline: 1.0013x; 1.0013x over previous
//
#include <hip/hip_runtime.h>
#include <stdint.h>

// ---------------------------------------------------------------------------
// AbstractAttention  B=2,S=2048,H=16,Dh=64,Dm=1024. fp32 in/out, bf16 MFMA.
// R15 == R14 resubmitted (previous round failed with an infra error, no
// measurement). R12 config (convall + bf16 QKV 128x128 + final 64x64) with
// ONE change vs R12: attn blockIdx->qt remap for per-CU balance. Old mapping
// gave CU c load 80-4*(c>>5) units (makespan 80 vs mean 66 -> 21% tail).
// New quartered mapping qt = {31-j, 16+j, 15-j, j} (quarter=bb>>8,
// j=(bb>>5)&7): every CU's 4 resident blocks sum to exactly 66 units under
// round-robin (b and b+256 share a CU for linear-RR or XCD-RR since
// 256 = 8*32). Body byte-identical (VGPR 64 codegen preserved); outputs
// bit-identical.
// ---------------------------------------------------------------------------

typedef __attribute__((ext_vector_type(8))) short short8;
typedef __attribute__((ext_vector_type(4))) short short4v;
typedef __attribute__((ext_vector_type(4))) float floatx4;
typedef __attribute__((ext_vector_type(4))) unsigned int uintx4;
typedef __attribute__((ext_vector_type(2))) unsigned int uint2v;

#define MFMA16(a, b, c) __builtin_amdgcn_mfma_f32_16x16x32_bf16(a, b, c, 0, 0, 0)

#if __has_builtin(__builtin_amdgcn_mfma_f32_16x16x16bf16_1k)
#define HAVE_K16 1
#define MFMAK16(a, b, c) __builtin_amdgcn_mfma_f32_16x16x16bf16_1k(a, b, c, 0, 0, 0)
#else
#define HAVE_K16 0
#endif

__device__ __forceinline__ unsigned short f2b(float f) {  // RNE fp32->bf16
  unsigned int u = __builtin_bit_cast(unsigned int, f);
  u = (u + 0x7fffu + ((u >> 16) & 1u)) >> 16;
  return (unsigned short)u;
}
__device__ __forceinline__ float exp2f_fast(float x) {
#if __has_builtin(__builtin_amdgcn_exp2f)
  return __builtin_amdgcn_exp2f(x);
#else
  return exp2f(x);
#endif
}
__device__ __forceinline__ unsigned int pack2_bf16(float lo, float hi) {
#if __has_builtin(__builtin_amdgcn_perm)
  return __builtin_amdgcn_perm(__builtin_bit_cast(unsigned int, hi),
                               __builtin_bit_cast(unsigned int, lo), 0x07060302u);
#else
  return (__builtin_bit_cast(unsigned int, lo) >> 16) |
         (__builtin_bit_cast(unsigned int, hi) & 0xffff0000u);
#endif
}

__device__ __forceinline__ void async_copy16(void* lds, const void* g) {
  __builtin_amdgcn_global_load_lds(
      (const __attribute__((address_space(1))) unsigned int*)g,
      (__attribute__((address_space(3))) unsigned int*)lds, 16, 0, 0);
}

// 4x4 transpose across lanes within col&3 groups (2 butterfly rounds).
__device__ __forceinline__ void xpose4(floatx4& v, int lane) {
  {
    float s0 = __shfl_xor(v[1], 1, 64);
    float s1 = __shfl_xor(v[0], 1, 64);
    float s2 = __shfl_xor(v[3], 1, 64);
    float s3 = __shfl_xor(v[2], 1, 64);
    if (lane & 1) { v[0] = s0; v[2] = s2; } else { v[1] = s1; v[3] = s3; }
  }
  {
    float s0 = __shfl_xor(v[2], 2, 64);
    float s1 = __shfl_xor(v[3], 2, 64);
    float s2 = __shfl_xor(v[0], 2, 64);
    float s3 = __shfl_xor(v[1], 2, 64);
    if (lane & 2) { v[0] = s0; v[1] = s1; } else { v[2] = s2; v[3] = s3; }
  }
}

// ---------------------------------------------------------------------------
// Fused conversions: one dispatch.
// blocks [0,12288): X fp32->bf16 (3 tensors)
// blocks [12288,13056): W_{Q,K,V} [h,d,e] -> [n=h*64+e][k=d]
// blocks [13056,13312): W_O [he,d] -> [n=d][k=he]
// ---------------------------------------------------------------------------
__global__ __launch_bounds__(256) void convall(
    const float* __restrict__ Xq, const float* __restrict__ Xk,
    const float* __restrict__ Xv, const float* __restrict__ WQ,
    const float* __restrict__ WK, const float* __restrict__ WV,
    const float* __restrict__ WO, unsigned short* __restrict__ xout,
    unsigned short* __restrict__ wout, unsigned short* __restrict__ woout) {
  __shared__ float T[64][65];
  const int bid = blockIdx.x;
  const int t = threadIdx.x;
  if (bid < 12288) {
    const int yy = bid / 4096, x = bid - yy * 4096;
    const float* in = (yy == 0) ? Xq : ((yy == 1) ? Xk : Xv);
    size_t i = (size_t)x * 256 + t;
    float4 v = ((const float4*)in)[i];
    ushort4 u;
    u.x = f2b(v.x); u.y = f2b(v.y); u.z = f2b(v.z); u.w = f2b(v.w);
    ((ushort4*)(xout + (size_t)yy * 4194304))[i] = u;
    return;
  }
  const int rr = t >> 4, cc = t & 15;
  if (bid < 13056) {
    const int sub = bid - 12288;
    const int yy = sub >> 8, x = sub & 255;
    const float* in = (yy == 0) ? WQ : ((yy == 1) ? WK : WV);
    const int h = x >> 4, d0 = (x & 15) << 6;
#pragma unroll
    for (int it = 0; it < 4; ++it) {
      int dl = it * 16 + rr;
      float4 v = *(const float4*)&in[(size_t)h * 65536 + (size_t)(d0 + dl) * 64 + cc * 4];
      T[dl][cc * 4 + 0] = v.x; T[dl][cc * 4 + 1] = v.y;
      T[dl][cc * 4 + 2] = v.z; T[dl][cc * 4 + 3] = v.w;
    }
    __syncthreads();
    unsigned short* ob = wout + (size_t)yy * 1048576;
#pragma unroll
    for (int it = 0; it < 4; ++it) {
      int e = it * 16 + rr;
      ushort4 u;
      u.x = f2b(T[cc * 4 + 0][e]); u.y = f2b(T[cc * 4 + 1][e]);
      u.z = f2b(T[cc * 4 + 2][e]); u.w = f2b(T[cc * 4 + 3][e]);
      *(ushort4*)&ob[(size_t)(h * 64 + e) * 1024 + d0 + cc * 4] = u;
    }
    return;
  }
  {
    const int x = bid - 13056;
    const int r0 = (x & 15) << 6, c0 = (x >> 4) << 6;
#pragma unroll
    for (int it = 0; it < 4; ++it) {
      int rl = it * 16 + rr;
      float4 v = *(const float4*)&WO[(size_t)(r0 + rl) * 1024 + c0 + cc * 4];
      T[rl][cc * 4 + 0] = v.x; T[rl][cc * 4 + 1] = v.y;
      T[rl][cc * 4 + 2] = v.z; T[rl][cc * 4 + 3] = v.w;
    }
    __syncthreads();
#pragma unroll
    for (int it = 0; it < 4; ++it) {
      int dl = it * 16 + rr;
      ushort4 u;
      u.x = f2b(T[cc * 4 + 0][dl]); u.y = f2b(T[cc * 4 + 1][dl]);
      u.z = f2b(T[cc * 4 + 2][dl]); u.w = f2b(T[cc * 4 + 3][dl]);
      *(ushort4*)&woout[(size_t)(c0 + dl) * 1024 + r0 + cc * 4] = u;
    }
  }
}

// ---------------------------------------------------------------------------
// GEMM, 8 waves / 512 threads, TM x TN tile, BK=64, 2-barrier loop.
// TM=128,TN=128: waves 4(m) x 2(n), wave tile 32x64 (MI=2,NJ=4). LDS 32KB.
// TM=64, TN=64 : waves 2(m) x 4(n), wave tile 32x16 (MI=2,NJ=1). LDS 16KB.
// Staging: 128B rows, slr=lane>>3 / sgc=(lane&7)^slr pre-swizzled global
// source, linear LDS dest (global_load_lds). Fragment read: block
// (kk*4+quad)^(col&7).
// NZ=3: z=0 q (mode1, qscale), z=1 k (mode1), z=2 v (mode2 [b,h,e,s]).
// NZ=1: fp32 [m][n] + bias (mode 0).
// ---------------------------------------------------------------------------
template <int TM, int TN, int NZ>
__global__ __launch_bounds__(512, (TM == 128) ? 6 : 4) void gemm512(
    const short* __restrict__ A0, const short* __restrict__ A1,
    const short* __restrict__ A2, const short* __restrict__ B0,
    const short* __restrict__ B1, const short* __restrict__ B2,
    const float* __restrict__ bias0, const float* __restrict__ bias1,
    const float* __restrict__ bias2, unsigned short* __restrict__ ob0,
    unsigned short* __restrict__ ob1, unsigned short* __restrict__ ob2,
    float* __restrict__ outf, float qscale) {
  constexpr int WAVES_N = (TN == 128) ? 2 : 4;
  constexpr int NJ = TN / (WAVES_N * 16);
  constexpr int NY = 4096 / TM;
  __shared__ short As[TM * 64];
  __shared__ short Bs[TN * 64];

  const int L = blockIdx.x;
  const int x = L / (NY * NZ);
  const int r = L - x * (NY * NZ);
  const int y = r / NZ;
  const int z = r - y * NZ;

  const short* A = (z == 0) ? A0 : (z == 1) ? A1 : A2;
  const short* Bt = (z == 0) ? B0 : (z == 1) ? B1 : B2;

  const int tid = threadIdx.x;
  const int lane = tid & 63, w = tid >> 6;
  const int quad = lane >> 4, col = lane & 15;
  const int m0 = y * TM, n0 = x * TN;
  const int wm = (w / WAVES_N) * 32, wn = (w % WAVES_N) * (NJ * 16);

  floatx4 acc[2][NJ] = {};

  // Staging geometry: 8 rows per async_copy16 call (8 lanes x 16B = 128B row).
  const int slr = lane >> 3, sgc = (lane & 7) ^ slr;
  // A: wave w covers rows [w*(TM/8), (w+1)*(TM/8)).
  const short* ga = A + (size_t)(m0 + w * (TM / 8) + slr) * 1024 + sgc * 8;
  // B: wave w covers rows [w*(TN/8), (w+1)*(TN/8)).
  const short* gb = Bt + (size_t)(n0 + w * (TN / 8) + slr) * 1024 + sgc * 8;
  const int fsw = col & 7;

  for (int k0 = 0; k0 < 1024; k0 += 64) {
    if (TM == 128) {
      async_copy16(&As[(w * 16) * 64], ga);
      async_copy16(&As[(w * 16 + 8) * 64], ga + 8 * 1024);
    } else {
      async_copy16(&As[(w * 8) * 64], ga);
    }
    if (TN == 128) {
      async_copy16(&Bs[(w * 16) * 64], gb);
      async_copy16(&Bs[(w * 16 + 8) * 64], gb + 8 * 1024);
    } else {
      async_copy16(&Bs[(w * 8) * 64], gb);
    }
    ga += 64; gb += 64;
    __syncthreads();
#pragma unroll
    for (int kk = 0; kk < 2; ++kk) {
      short8 af[2], bf[NJ];
#pragma unroll
      for (int mi = 0; mi < 2; ++mi)
        af[mi] = *(const short8*)&As[(wm + mi * 16 + col) * 64 +
                                     (((kk * 4 + quad) ^ fsw) * 8)];
#pragma unroll
      for (int nj = 0; nj < NJ; ++nj)
        bf[nj] = *(const short8*)&Bs[(wn + nj * 16 + col) * 64 +
                                     (((kk * 4 + quad) ^ fsw) * 8)];
#pragma unroll
      for (int mi = 0; mi < 2; ++mi)
#pragma unroll
        for (int nj = 0; nj < NJ; ++nj)
          acc[mi][nj] = MFMA16(af[mi], bf[nj], acc[mi][nj]);
    }
    __syncthreads();
  }

  const float* bias = (z == 0) ? bias0 : (z == 1) ? bias1 : bias2;
  unsigned short* outb = (z == 0) ? ob0 : (z == 1) ? ob1 : ob2;
  const int mode = (NZ == 3) ? ((z == 2) ? 2 : 1) : 0;
  const float scale = (NZ == 3 && z == 0) ? qscale : 1.0f;

  float bv[NJ];
#pragma unroll
  for (int nj = 0; nj < NJ; ++nj) bv[nj] = bias[n0 + wn + nj * 16 + col];

  if (mode == 2) {
#pragma unroll
    for (int mi = 0; mi < 2; ++mi)
#pragma unroll
      for (int nj = 0; nj < NJ; ++nj) {
        int m = m0 + wm + mi * 16 + quad * 4;
        int n = n0 + wn + nj * 16 + col;
        int bb = m >> 11, s = m & 2047, h = n >> 6, e = n & 63;
        ushort4 u;
        u.x = f2b(acc[mi][nj][0] + bv[nj]);
        u.y = f2b(acc[mi][nj][1] + bv[nj]);
        u.z = f2b(acc[mi][nj][2] + bv[nj]);
        u.w = f2b(acc[mi][nj][3] + bv[nj]);
        *(ushort4*)&outb[(((size_t)bb * 16 + h) * 64 + e) * 2048 + s] = u;
      }
  } else {
#pragma unroll
    for (int mi = 0; mi < 2; ++mi)
#pragma unroll
      for (int nj = 0; nj < NJ; ++nj) {
        floatx4 v;
#pragma unroll
        for (int rr = 0; rr < 4; ++rr) v[rr] = (acc[mi][nj][rr] + bv[nj]) * scale;
        xpose4(v, lane);
        int m = m0 + wm + mi * 16 + quad * 4 + (col & 3);
        int nb = n0 + wn + nj * 16 + (col & ~3);
        if (mode == 0) {
          *(floatx4*)&outf[(size_t)m * 1024 + nb] = v;
        } else {
          int bb = m >> 11, s = m & 2047, h = nb >> 6, e = nb & 63;
          ushort4 u;
          u.x = f2b(v[0]); u.y = f2b(v[1]); u.z = f2b(v[2]); u.w = f2b(v[3]);
          *(ushort4*)&outb[(((size_t)bb * 16 + h) * 2048 + s) * 64 + e] = u;
        }
      }
  }
}

// ---------------------------------------------------------------------------
// Flash attention (causal), S^T formulation, 64 q/block, double-buffered K/V,
// PV via K=16 MFMA (P^T C-layout == 16x16x16 B-frag layout).
// Body R6-verbatim; only the blockIdx->qt mapping changed (per-CU balance:
// quartered map, 66 units/CU exactly under round-robin).
// ---------------------------------------------------------------------------
#if !HAVE_K16
__device__ __forceinline__ void exchange4(const unsigned int* u01,
                                          const unsigned int* u23, int srcA,
                                          int srcB, bool hiq, short8& pf0,
                                          short8& pf1) {
  unsigned int xA0 = (unsigned int)__shfl((int)u01[0], srcA, 64);
  unsigned int xA1 = (unsigned int)__shfl((int)u01[1], srcA, 64);
  unsigned int yA0 = (unsigned int)__shfl((int)u23[0], srcA, 64);
  unsigned int yA1 = (unsigned int)__shfl((int)u23[1], srcA, 64);
  unsigned int xB0 = (unsigned int)__shfl((int)u01[0], srcB, 64);
  unsigned int xB1 = (unsigned int)__shfl((int)u01[1], srcB, 64);
  unsigned int yB0 = (unsigned int)__shfl((int)u23[0], srcB, 64);
  unsigned int yB1 = (unsigned int)__shfl((int)u23[1], srcB, 64);
  uintx4 v0;
  v0.x = hiq ? xA1 : xA0; v0.y = hiq ? yA1 : yA0;
  v0.z = hiq ? xB1 : xB0; v0.w = hiq ? yB1 : yB0;
  pf0 = __builtin_bit_cast(short8, v0);
  xA0 = (unsigned int)__shfl((int)u01[2], srcA, 64);
  xA1 = (unsigned int)__shfl((int)u01[3], srcA, 64);
  yA0 = (unsigned int)__shfl((int)u23[2], srcA, 64);
  yA1 = (unsigned int)__shfl((int)u23[3], srcA, 64);
  xB0 = (unsigned int)__shfl((int)u01[2], srcB, 64);
  xB1 = (unsigned int)__shfl((int)u01[3], srcB, 64);
  yB0 = (unsigned int)__shfl((int)u23[2], srcB, 64);
  yB1 = (unsigned int)__shfl((int)u23[3], srcB, 64);
  uintx4 v1;
  v1.x = hiq ? xA1 : xA0; v1.y = hiq ? yA1 : yA0;
  v1.z = hiq ? xB1 : xB0; v1.w = hiq ? yB1 : yB0;
  pf1 = __builtin_bit_cast(short8, v1);
}
#endif

__device__ __forceinline__ void stage_kv(short* Kbuf, short* Vbuf,
                                         const short* kg, const short* vg,
                                         int kv0, int w, int slr, int sgc) {
  const short* kr = kg + (size_t)(kv0 + w * 16 + slr) * 64 + sgc * 8;
  async_copy16(&Kbuf[(w * 16) * 64], kr);
  async_copy16(&Kbuf[(w * 16 + 8) * 64], kr + 8 * 64);
  const short* vr = vg + (size_t)(w * 16 + slr) * 2048 + kv0 + sgc * 8;
  async_copy16(&Vbuf[(w * 16) * 64], vr);
  async_copy16(&Vbuf[(w * 16 + 8) * 64], vr + 8 * 2048);
}

__global__ __launch_bounds__(256) void attn(const short* __restrict__ q,
                                            const short* __restrict__ k,
                                            const short* __restrict__ vt,
                                            unsigned short* __restrict__ z) {
  __shared__ short Ks[2][64 * 64];
  __shared__ short Vs[2][64 * 64];

  const int tid = threadIdx.x;
  const int lane = tid & 63, w = tid >> 6;
  const int quad = lane >> 4, col = lane & 15;
  // Quartered qt map: CU c's four resident blocks {c, c+256, c+512, c+768}
  // get qt {31-j, 16+j, 15-j, j} (j = (bb>>5)&7) -> 66 units per CU exactly.
  const int bbi = blockIdx.x;
  const int quarter = bbi >> 8;
  const int j = (bbi >> 5) & 7;
  const int bh = bbi & 31;
  const int qt = (quarter == 0) ? (31 - j)
               : (quarter == 1) ? (16 + j)
               : (quarter == 2) ? (15 - j)
                                : j;
  const int q0 = qt * 64, qw0 = q0 + w * 16;
  const size_t base = (size_t)bh * (2048 * 64);

  const short* qp = q + base + (size_t)(qw0 + col) * 64 + quad * 8;
  short8 bq0 = *(const short8*)qp;
  short8 bq1 = *(const short8*)(qp + 32);

  floatx4 o[4] = {};
  float m_run = -1e30f, l_run = 0.f;

  const short* kg = k + base;
  const short* vg = vt + base;
  const int ksw = col & 7;
  const int slr = lane >> 3, sgc = (lane & 7) ^ slr;
#if !HAVE_K16
  const int srcA = ((quad & 1) << 5) + col, srcB = srcA + 16;
  const bool hiq = (quad & 2) != 0;
#endif

  stage_kv(Ks[0], Vs[0], kg, vg, 0, w, slr, sgc);
  int p = 0;

  for (int t = 0; t <= qt; ++t) {
    __syncthreads();
    if (t < qt) stage_kv(Ks[p ^ 1], Vs[p ^ 1], kg, vg, (t + 1) * 64, w, slr, sgc);

    const bool diag = (t == qt);
    const int mtmax = diag ? w : 3;

    floatx4 st[4];
#pragma unroll
    for (int mt = 0; mt < 4; ++mt) {
      if (mt <= mtmax) {
        const short* kb = &Ks[p][(mt * 16 + col) * 64];
        short8 ka0 = *(const short8*)(kb + (quad ^ ksw) * 8);
        short8 ka1 = *(const short8*)(kb + ((quad + 4) ^ ksw) * 8);
        floatx4 a = {0.f, 0.f, 0.f, 0.f};
        a = MFMA16(ka0, bq0, a);
        a = MFMA16(ka1, bq1, a);
        if (diag && mt == mtmax) {
#pragma unroll
          for (int r = 0; r < 4; ++r)
            if (quad * 4 + r > col) a[r] = -1e9f;
        }
        st[mt] = a;
      }
    }

    float pmax = -3e38f;
#pragma unroll
    for (int mt = 0; mt < 4; ++mt)
      if (mt <= mtmax) {
#pragma unroll
        for (int r = 0; r < 4; ++r) pmax = fmaxf(pmax, st[mt][r]);
      }
    pmax = fmaxf(pmax, __shfl_xor(pmax, 16, 64));
    pmax = fmaxf(pmax, __shfl_xor(pmax, 32, 64));
    float mnew = fmaxf(m_run, pmax);
    float alpha = exp2f_fast(m_run - mnew);
    m_run = mnew;

    unsigned int u01[4], u23[4];
    float lsum = 0.f;
#pragma unroll
    for (int mt = 0; mt < 4; ++mt) {
      if (mt <= mtmax) {
        float p0 = exp2f_fast(st[mt][0] - mnew);
        float p1 = exp2f_fast(st[mt][1] - mnew);
        float p2 = exp2f_fast(st[mt][2] - mnew);
        float p3 = exp2f_fast(st[mt][3] - mnew);
        lsum += (p0 + p1) + (p2 + p3);
        u01[mt] = pack2_bf16(p0, p1);
        u23[mt] = pack2_bf16(p2, p3);
      } else {
        u01[mt] = 0u; u23[mt] = 0u;
      }
    }
    lsum += __shfl_xor(lsum, 16, 64);
    lsum += __shfl_xor(lsum, 32, 64);
    l_run = l_run * alpha + lsum;

#if HAVE_K16
    short4v pb[4];
#pragma unroll
    for (int mt = 0; mt < 4; ++mt) {
      uint2v uu;
      uu.x = u01[mt]; uu.y = u23[mt];
      pb[mt] = __builtin_bit_cast(short4v, uu);
    }
#pragma unroll
    for (int et = 0; et < 4; ++et) {
      const short* vrow = &Vs[p][(et * 16 + col) * 64];
      floatx4 t0 = o[et];
#pragma unroll
      for (int r = 0; r < 4; ++r) t0[r] *= alpha;
#pragma unroll
      for (int mt = 0; mt < 4; ++mt) {
        if (mt <= mtmax) {
          int c = mt * 2 + (quad >> 1);
          short4v va = *(const short4v*)&vrow[((c ^ ksw) * 8) + (quad & 1) * 4];
          t0 = MFMAK16(va, pb[mt], t0);
        }
      }
      o[et] = t0;
    }
#else
    short8 pf0, pf1;
    exchange4(u01, u23, srcA, srcB, hiq, pf0, pf1);
#pragma unroll
    for (int et = 0; et < 4; ++et) {
      const short* vb = &Vs[p][(et * 16 + col) * 64];
      short8 va0 = *(const short8*)(vb + (quad ^ ksw) * 8);
      short8 va1 = *(const short8*)(vb + ((quad + 4) ^ ksw) * 8);
      floatx4 t0 = o[et];
#pragma unroll
      for (int r = 0; r < 4; ++r) t0[r] *= alpha;
      t0 = MFMA16(va0, pf0, t0);
      t0 = MFMA16(va1, pf1, t0);
      o[et] = t0;
    }
#endif
    p ^= 1;
  }

  const int b = bh >> 4, h = bh & 15;
#if __has_builtin(__builtin_amdgcn_rcpf)
  const float invl = __builtin_amdgcn_rcpf(l_run);
#else
  const float invl = 1.f / l_run;
#endif
  unsigned short* zr = z + (((size_t)b * 2048 + qw0 + col) * 16 + h) * 64;
#pragma unroll
  for (int et = 0; et < 4; ++et) {
    ushort4 u;
    u.x = f2b(o[et][0] * invl); u.y = f2b(o[et][1] * invl);
    u.z = f2b(o[et][2] * invl); u.w = f2b(o[et][3] * invl);
    *(ushort4*)&zr[et * 16 + quad * 4] = u;
  }
}

// ---------------------------------------------------------------------------
extern "C" void kernel_launch(void* const* d_in, const int* in_sizes, int n_in,
                              void* d_out, int out_size, void* d_ws, size_t ws_size,
                              hipStream_t stream) {
  (void)in_sizes; (void)n_in; (void)out_size; (void)ws_size;
  const float* Xq = (const float*)d_in[0];
  const float* Xk = (const float*)d_in[1];
  const float* Xv = (const float*)d_in[2];
  const float* WQ = (const float*)d_in[3];
  const float* WK = (const float*)d_in[4];
  const float* WV = (const float*)d_in[5];
  const float* WO = (const float*)d_in[6];
  const float* bQ = (const float*)d_in[7];
  const float* bK = (const float*)d_in[8];
  const float* bV = (const float*)d_in[9];
  const float* bO = (const float*)d_in[10];
  float* out = (float*)d_out;

  unsigned short* xqb = (unsigned short*)d_ws;
  unsigned short* xkb = xqb + 4194304;
  unsigned short* xvb = xkb + 4194304;
  unsigned short* wqt = xvb + 4194304;
  unsigned short* wkt = wqt + 1048576;
  unsigned short* wvt = wkt + 1048576;
  unsigned short* wot = wvt + 1048576;
  unsigned short* qb = wot + 1048576;
  unsigned short* kb = qb + 4194304;
  unsigned short* vtb = kb + 4194304;
  unsigned short* zb = vtb + 4194304;

  convall<<<13312, 256, 0, stream>>>(Xq, Xk, Xv, WQ, WK, WV, WO, xqb, wqt, wot);

  const float qscale = 0.125f * 1.44269504088896f;  // 1/sqrt(64) * log2(e)
  gemm512<128, 128, 3><<<768, 512, 0, stream>>>(
      (const short*)xqb, (const short*)xkb, (const short*)xvb,
      (const short*)wqt, (const short*)wkt, (const short*)wvt, bQ, bK, bV, qb,
      kb, vtb, nullptr, qscale);

  attn<<<1024, 256, 0, stream>>>((const short*)qb, (const short*)kb,
                                 (const short*)vtb, zb);

  gemm512<64, 64, 1><<<1024, 512, 0, stream>>>(
      (const short*)zb, (const short*)zb, (const short*)zb, (const short*)wot,
      (const short*)wot, (const short*)wot, bO, bO, bO, nullptr, nullptr,
      nullptr, out, 1.0f);
}

// Round 10
// 209.942 us; speedup vs baseline: 1.0548x; 1.0534x over previous
//
#include <hip/hip_runtime.h>
#include <stdint.h>

// ---------------------------------------------------------------------------
// AbstractAttention  B=2,S=2048,H=16,Dh=64,Dm=1024. fp32 in/out, bf16 MFMA.
// R16: R15 post-mortem falsified the CU-balance model -- attn makespan = the
// longest single block's SERIAL chain (32 units x ~1.58us), so remaps are
// neutral and only per-unit latency matters. Codegen-safe lever: s_setprio(1)
// around the QK and PV MFMA clusters (T5; guide m191 measured +4-7% on attn
// in exactly this regime: co-resident blocks at different phases). qt map
// reverted to R6 original. GEMMs (BK=64, QKV 128x128, final 64x64) and
// convall unchanged from R12. Body otherwise R6-verbatim (VGPR 64).
// ---------------------------------------------------------------------------

typedef __attribute__((ext_vector_type(8))) short short8;
typedef __attribute__((ext_vector_type(4))) short short4v;
typedef __attribute__((ext_vector_type(4))) float floatx4;
typedef __attribute__((ext_vector_type(4))) unsigned int uintx4;
typedef __attribute__((ext_vector_type(2))) unsigned int uint2v;

#define MFMA16(a, b, c) __builtin_amdgcn_mfma_f32_16x16x32_bf16(a, b, c, 0, 0, 0)

#if __has_builtin(__builtin_amdgcn_mfma_f32_16x16x16bf16_1k)
#define HAVE_K16 1
#define MFMAK16(a, b, c) __builtin_amdgcn_mfma_f32_16x16x16bf16_1k(a, b, c, 0, 0, 0)
#else
#define HAVE_K16 0
#endif

__device__ __forceinline__ unsigned short f2b(float f) {  // RNE fp32->bf16
  unsigned int u = __builtin_bit_cast(unsigned int, f);
  u = (u + 0x7fffu + ((u >> 16) & 1u)) >> 16;
  return (unsigned short)u;
}
__device__ __forceinline__ float exp2f_fast(float x) {
#if __has_builtin(__builtin_amdgcn_exp2f)
  return __builtin_amdgcn_exp2f(x);
#else
  return exp2f(x);
#endif
}
__device__ __forceinline__ unsigned int pack2_bf16(float lo, float hi) {
#if __has_builtin(__builtin_amdgcn_perm)
  return __builtin_amdgcn_perm(__builtin_bit_cast(unsigned int, hi),
                               __builtin_bit_cast(unsigned int, lo), 0x07060302u);
#else
  return (__builtin_bit_cast(unsigned int, lo) >> 16) |
         (__builtin_bit_cast(unsigned int, hi) & 0xffff0000u);
#endif
}

__device__ __forceinline__ void async_copy16(void* lds, const void* g) {
  __builtin_amdgcn_global_load_lds(
      (const __attribute__((address_space(1))) unsigned int*)g,
      (__attribute__((address_space(3))) unsigned int*)lds, 16, 0, 0);
}

// 4x4 transpose across lanes within col&3 groups (2 butterfly rounds).
__device__ __forceinline__ void xpose4(floatx4& v, int lane) {
  {
    float s0 = __shfl_xor(v[1], 1, 64);
    float s1 = __shfl_xor(v[0], 1, 64);
    float s2 = __shfl_xor(v[3], 1, 64);
    float s3 = __shfl_xor(v[2], 1, 64);
    if (lane & 1) { v[0] = s0; v[2] = s2; } else { v[1] = s1; v[3] = s3; }
  }
  {
    float s0 = __shfl_xor(v[2], 2, 64);
    float s1 = __shfl_xor(v[3], 2, 64);
    float s2 = __shfl_xor(v[0], 2, 64);
    float s3 = __shfl_xor(v[1], 2, 64);
    if (lane & 2) { v[0] = s0; v[1] = s1; } else { v[2] = s2; v[3] = s3; }
  }
}

// ---------------------------------------------------------------------------
// Fused conversions: one dispatch.
// blocks [0,12288): X fp32->bf16 (3 tensors)
// blocks [12288,13056): W_{Q,K,V} [h,d,e] -> [n=h*64+e][k=d]
// blocks [13056,13312): W_O [he,d] -> [n=d][k=he]
// ---------------------------------------------------------------------------
__global__ __launch_bounds__(256) void convall(
    const float* __restrict__ Xq, const float* __restrict__ Xk,
    const float* __restrict__ Xv, const float* __restrict__ WQ,
    const float* __restrict__ WK, const float* __restrict__ WV,
    const float* __restrict__ WO, unsigned short* __restrict__ xout,
    unsigned short* __restrict__ wout, unsigned short* __restrict__ woout) {
  __shared__ float T[64][65];
  const int bid = blockIdx.x;
  const int t = threadIdx.x;
  if (bid < 12288) {
    const int yy = bid / 4096, x = bid - yy * 4096;
    const float* in = (yy == 0) ? Xq : ((yy == 1) ? Xk : Xv);
    size_t i = (size_t)x * 256 + t;
    float4 v = ((const float4*)in)[i];
    ushort4 u;
    u.x = f2b(v.x); u.y = f2b(v.y); u.z = f2b(v.z); u.w = f2b(v.w);
    ((ushort4*)(xout + (size_t)yy * 4194304))[i] = u;
    return;
  }
  const int rr = t >> 4, cc = t & 15;
  if (bid < 13056) {
    const int sub = bid - 12288;
    const int yy = sub >> 8, x = sub & 255;
    const float* in = (yy == 0) ? WQ : ((yy == 1) ? WK : WV);
    const int h = x >> 4, d0 = (x & 15) << 6;
#pragma unroll
    for (int it = 0; it < 4; ++it) {
      int dl = it * 16 + rr;
      float4 v = *(const float4*)&in[(size_t)h * 65536 + (size_t)(d0 + dl) * 64 + cc * 4];
      T[dl][cc * 4 + 0] = v.x; T[dl][cc * 4 + 1] = v.y;
      T[dl][cc * 4 + 2] = v.z; T[dl][cc * 4 + 3] = v.w;
    }
    __syncthreads();
    unsigned short* ob = wout + (size_t)yy * 1048576;
#pragma unroll
    for (int it = 0; it < 4; ++it) {
      int e = it * 16 + rr;
      ushort4 u;
      u.x = f2b(T[cc * 4 + 0][e]); u.y = f2b(T[cc * 4 + 1][e]);
      u.z = f2b(T[cc * 4 + 2][e]); u.w = f2b(T[cc * 4 + 3][e]);
      *(ushort4*)&ob[(size_t)(h * 64 + e) * 1024 + d0 + cc * 4] = u;
    }
    return;
  }
  {
    const int x = bid - 13056;
    const int r0 = (x & 15) << 6, c0 = (x >> 4) << 6;
#pragma unroll
    for (int it = 0; it < 4; ++it) {
      int rl = it * 16 + rr;
      float4 v = *(const float4*)&WO[(size_t)(r0 + rl) * 1024 + c0 + cc * 4];
      T[rl][cc * 4 + 0] = v.x; T[rl][cc * 4 + 1] = v.y;
      T[rl][cc * 4 + 2] = v.z; T[rl][cc * 4 + 3] = v.w;
    }
    __syncthreads();
#pragma unroll
    for (int it = 0; it < 4; ++it) {
      int dl = it * 16 + rr;
      ushort4 u;
      u.x = f2b(T[cc * 4 + 0][dl]); u.y = f2b(T[cc * 4 + 1][dl]);
      u.z = f2b(T[cc * 4 + 2][dl]); u.w = f2b(T[cc * 4 + 3][dl]);
      *(ushort4*)&woout[(size_t)(c0 + dl) * 1024 + r0 + cc * 4] = u;
    }
  }
}

// ---------------------------------------------------------------------------
// GEMM, 8 waves / 512 threads, TM x TN tile, BK=64, 2-barrier loop.
// TM=128,TN=128: waves 4(m) x 2(n), wave tile 32x64 (MI=2,NJ=4). LDS 32KB.
// TM=64, TN=64 : waves 2(m) x 4(n), wave tile 32x16 (MI=2,NJ=1). LDS 16KB.
// Staging: 128B rows, slr=lane>>3 / sgc=(lane&7)^slr pre-swizzled global
// source, linear LDS dest (global_load_lds). Fragment read: block
// (kk*4+quad)^(col&7).
// NZ=3: z=0 q (mode1, qscale), z=1 k (mode1), z=2 v (mode2 [b,h,e,s]).
// NZ=1: fp32 [m][n] + bias (mode 0).
// ---------------------------------------------------------------------------
template <int TM, int TN, int NZ>
__global__ __launch_bounds__(512, (TM == 128) ? 6 : 4) void gemm512(
    const short* __restrict__ A0, const short* __restrict__ A1,
    const short* __restrict__ A2, const short* __restrict__ B0,
    const short* __restrict__ B1, const short* __restrict__ B2,
    const float* __restrict__ bias0, const float* __restrict__ bias1,
    const float* __restrict__ bias2, unsigned short* __restrict__ ob0,
    unsigned short* __restrict__ ob1, unsigned short* __restrict__ ob2,
    float* __restrict__ outf, float qscale) {
  constexpr int WAVES_N = (TN == 128) ? 2 : 4;
  constexpr int NJ = TN / (WAVES_N * 16);
  constexpr int NY = 4096 / TM;
  __shared__ short As[TM * 64];
  __shared__ short Bs[TN * 64];

  const int L = blockIdx.x;
  const int x = L / (NY * NZ);
  const int r = L - x * (NY * NZ);
  const int y = r / NZ;
  const int z = r - y * NZ;

  const short* A = (z == 0) ? A0 : (z == 1) ? A1 : A2;
  const short* Bt = (z == 0) ? B0 : (z == 1) ? B1 : B2;

  const int tid = threadIdx.x;
  const int lane = tid & 63, w = tid >> 6;
  const int quad = lane >> 4, col = lane & 15;
  const int m0 = y * TM, n0 = x * TN;
  const int wm = (w / WAVES_N) * 32, wn = (w % WAVES_N) * (NJ * 16);

  floatx4 acc[2][NJ] = {};

  // Staging geometry: 8 rows per async_copy16 call (8 lanes x 16B = 128B row).
  const int slr = lane >> 3, sgc = (lane & 7) ^ slr;
  // A: wave w covers rows [w*(TM/8), (w+1)*(TM/8)).
  const short* ga = A + (size_t)(m0 + w * (TM / 8) + slr) * 1024 + sgc * 8;
  // B: wave w covers rows [w*(TN/8), (w+1)*(TN/8)).
  const short* gb = Bt + (size_t)(n0 + w * (TN / 8) + slr) * 1024 + sgc * 8;
  const int fsw = col & 7;

  for (int k0 = 0; k0 < 1024; k0 += 64) {
    if (TM == 128) {
      async_copy16(&As[(w * 16) * 64], ga);
      async_copy16(&As[(w * 16 + 8) * 64], ga + 8 * 1024);
    } else {
      async_copy16(&As[(w * 8) * 64], ga);
    }
    if (TN == 128) {
      async_copy16(&Bs[(w * 16) * 64], gb);
      async_copy16(&Bs[(w * 16 + 8) * 64], gb + 8 * 1024);
    } else {
      async_copy16(&Bs[(w * 8) * 64], gb);
    }
    ga += 64; gb += 64;
    __syncthreads();
#pragma unroll
    for (int kk = 0; kk < 2; ++kk) {
      short8 af[2], bf[NJ];
#pragma unroll
      for (int mi = 0; mi < 2; ++mi)
        af[mi] = *(const short8*)&As[(wm + mi * 16 + col) * 64 +
                                     (((kk * 4 + quad) ^ fsw) * 8)];
#pragma unroll
      for (int nj = 0; nj < NJ; ++nj)
        bf[nj] = *(const short8*)&Bs[(wn + nj * 16 + col) * 64 +
                                     (((kk * 4 + quad) ^ fsw) * 8)];
#pragma unroll
      for (int mi = 0; mi < 2; ++mi)
#pragma unroll
        for (int nj = 0; nj < NJ; ++nj)
          acc[mi][nj] = MFMA16(af[mi], bf[nj], acc[mi][nj]);
    }
    __syncthreads();
  }

  const float* bias = (z == 0) ? bias0 : (z == 1) ? bias1 : bias2;
  unsigned short* outb = (z == 0) ? ob0 : (z == 1) ? ob1 : ob2;
  const int mode = (NZ == 3) ? ((z == 2) ? 2 : 1) : 0;
  const float scale = (NZ == 3 && z == 0) ? qscale : 1.0f;

  float bv[NJ];
#pragma unroll
  for (int nj = 0; nj < NJ; ++nj) bv[nj] = bias[n0 + wn + nj * 16 + col];

  if (mode == 2) {
#pragma unroll
    for (int mi = 0; mi < 2; ++mi)
#pragma unroll
      for (int nj = 0; nj < NJ; ++nj) {
        int m = m0 + wm + mi * 16 + quad * 4;
        int n = n0 + wn + nj * 16 + col;
        int bb = m >> 11, s = m & 2047, h = n >> 6, e = n & 63;
        ushort4 u;
        u.x = f2b(acc[mi][nj][0] + bv[nj]);
        u.y = f2b(acc[mi][nj][1] + bv[nj]);
        u.z = f2b(acc[mi][nj][2] + bv[nj]);
        u.w = f2b(acc[mi][nj][3] + bv[nj]);
        *(ushort4*)&outb[(((size_t)bb * 16 + h) * 64 + e) * 2048 + s] = u;
      }
  } else {
#pragma unroll
    for (int mi = 0; mi < 2; ++mi)
#pragma unroll
      for (int nj = 0; nj < NJ; ++nj) {
        floatx4 v;
#pragma unroll
        for (int rr = 0; rr < 4; ++rr) v[rr] = (acc[mi][nj][rr] + bv[nj]) * scale;
        xpose4(v, lane);
        int m = m0 + wm + mi * 16 + quad * 4 + (col & 3);
        int nb = n0 + wn + nj * 16 + (col & ~3);
        if (mode == 0) {
          *(floatx4*)&outf[(size_t)m * 1024 + nb] = v;
        } else {
          int bb = m >> 11, s = m & 2047, h = nb >> 6, e = nb & 63;
          ushort4 u;
          u.x = f2b(v[0]); u.y = f2b(v[1]); u.z = f2b(v[2]); u.w = f2b(v[3]);
          *(ushort4*)&outb[(((size_t)bb * 16 + h) * 2048 + s) * 64 + e] = u;
        }
      }
  }
}

// ---------------------------------------------------------------------------
// Flash attention (causal), S^T formulation, 64 q/block, double-buffered K/V,
// PV via K=16 MFMA (P^T C-layout == 16x16x16 B-frag layout).
// R16: R6 body + s_setprio(1)/(0) around the QK and PV MFMA clusters (T5).
// ---------------------------------------------------------------------------
#if !HAVE_K16
__device__ __forceinline__ void exchange4(const unsigned int* u01,
                                          const unsigned int* u23, int srcA,
                                          int srcB, bool hiq, short8& pf0,
                                          short8& pf1) {
  unsigned int xA0 = (unsigned int)__shfl((int)u01[0], srcA, 64);
  unsigned int xA1 = (unsigned int)__shfl((int)u01[1], srcA, 64);
  unsigned int yA0 = (unsigned int)__shfl((int)u23[0], srcA, 64);
  unsigned int yA1 = (unsigned int)__shfl((int)u23[1], srcA, 64);
  unsigned int xB0 = (unsigned int)__shfl((int)u01[0], srcB, 64);
  unsigned int xB1 = (unsigned int)__shfl((int)u01[1], srcB, 64);
  unsigned int yB0 = (unsigned int)__shfl((int)u23[0], srcB, 64);
  unsigned int yB1 = (unsigned int)__shfl((int)u23[1], srcB, 64);
  uintx4 v0;
  v0.x = hiq ? xA1 : xA0; v0.y = hiq ? yA1 : yA0;
  v0.z = hiq ? xB1 : xB0; v0.w = hiq ? yB1 : yB0;
  pf0 = __builtin_bit_cast(short8, v0);
  xA0 = (unsigned int)__shfl((int)u01[2], srcA, 64);
  xA1 = (unsigned int)__shfl((int)u01[3], srcA, 64);
  yA0 = (unsigned int)__shfl((int)u23[2], srcA, 64);
  yA1 = (unsigned int)__shfl((int)u23[3], srcA, 64);
  xB0 = (unsigned int)__shfl((int)u01[2], srcB, 64);
  xB1 = (unsigned int)__shfl((int)u01[3], srcB, 64);
  yB0 = (unsigned int)__shfl((int)u23[2], srcB, 64);
  yB1 = (unsigned int)__shfl((int)u23[3], srcB, 64);
  uintx4 v1;
  v1.x = hiq ? xA1 : xA0; v1.y = hiq ? yA1 : yA0;
  v1.z = hiq ? xB1 : xB0; v1.w = hiq ? yB1 : yB0;
  pf1 = __builtin_bit_cast(short8, v1);
}
#endif

__device__ __forceinline__ void stage_kv(short* Kbuf, short* Vbuf,
                                         const short* kg, const short* vg,
                                         int kv0, int w, int slr, int sgc) {
  const short* kr = kg + (size_t)(kv0 + w * 16 + slr) * 64 + sgc * 8;
  async_copy16(&Kbuf[(w * 16) * 64], kr);
  async_copy16(&Kbuf[(w * 16 + 8) * 64], kr + 8 * 64);
  const short* vr = vg + (size_t)(w * 16 + slr) * 2048 + kv0 + sgc * 8;
  async_copy16(&Vbuf[(w * 16) * 64], vr);
  async_copy16(&Vbuf[(w * 16 + 8) * 64], vr + 8 * 2048);
}

__global__ __launch_bounds__(256) void attn(const short* __restrict__ q,
                                            const short* __restrict__ k,
                                            const short* __restrict__ vt,
                                            unsigned short* __restrict__ z) {
  __shared__ short Ks[2][64 * 64];
  __shared__ short Vs[2][64 * 64];

  const int tid = threadIdx.x;
  const int lane = tid & 63, w = tid >> 6;
  const int quad = lane >> 4, col = lane & 15;
  const int qt = 31 - (blockIdx.x >> 5), bh = blockIdx.x & 31;
  const int q0 = qt * 64, qw0 = q0 + w * 16;
  const size_t base = (size_t)bh * (2048 * 64);

  const short* qp = q + base + (size_t)(qw0 + col) * 64 + quad * 8;
  short8 bq0 = *(const short8*)qp;
  short8 bq1 = *(const short8*)(qp + 32);

  floatx4 o[4] = {};
  float m_run = -1e30f, l_run = 0.f;

  const short* kg = k + base;
  const short* vg = vt + base;
  const int ksw = col & 7;
  const int slr = lane >> 3, sgc = (lane & 7) ^ slr;
#if !HAVE_K16
  const int srcA = ((quad & 1) << 5) + col, srcB = srcA + 16;
  const bool hiq = (quad & 2) != 0;
#endif

  stage_kv(Ks[0], Vs[0], kg, vg, 0, w, slr, sgc);
  int p = 0;

  for (int t = 0; t <= qt; ++t) {
    __syncthreads();
    if (t < qt) stage_kv(Ks[p ^ 1], Vs[p ^ 1], kg, vg, (t + 1) * 64, w, slr, sgc);

    const bool diag = (t == qt);
    const int mtmax = diag ? w : 3;

    floatx4 st[4];
    __builtin_amdgcn_s_setprio(1);
#pragma unroll
    for (int mt = 0; mt < 4; ++mt) {
      if (mt <= mtmax) {
        const short* kb = &Ks[p][(mt * 16 + col) * 64];
        short8 ka0 = *(const short8*)(kb + (quad ^ ksw) * 8);
        short8 ka1 = *(const short8*)(kb + ((quad + 4) ^ ksw) * 8);
        floatx4 a = {0.f, 0.f, 0.f, 0.f};
        a = MFMA16(ka0, bq0, a);
        a = MFMA16(ka1, bq1, a);
        if (diag && mt == mtmax) {
#pragma unroll
          for (int r = 0; r < 4; ++r)
            if (quad * 4 + r > col) a[r] = -1e9f;
        }
        st[mt] = a;
      }
    }
    __builtin_amdgcn_s_setprio(0);

    float pmax = -3e38f;
#pragma unroll
    for (int mt = 0; mt < 4; ++mt)
      if (mt <= mtmax) {
#pragma unroll
        for (int r = 0; r < 4; ++r) pmax = fmaxf(pmax, st[mt][r]);
      }
    pmax = fmaxf(pmax, __shfl_xor(pmax, 16, 64));
    pmax = fmaxf(pmax, __shfl_xor(pmax, 32, 64));
    float mnew = fmaxf(m_run, pmax);
    float alpha = exp2f_fast(m_run - mnew);
    m_run = mnew;

    unsigned int u01[4], u23[4];
    float lsum = 0.f;
#pragma unroll
    for (int mt = 0; mt < 4; ++mt) {
      if (mt <= mtmax) {
        float p0 = exp2f_fast(st[mt][0] - mnew);
        float p1 = exp2f_fast(st[mt][1] - mnew);
        float p2 = exp2f_fast(st[mt][2] - mnew);
        float p3 = exp2f_fast(st[mt][3] - mnew);
        lsum += (p0 + p1) + (p2 + p3);
        u01[mt] = pack2_bf16(p0, p1);
        u23[mt] = pack2_bf16(p2, p3);
      } else {
        u01[mt] = 0u; u23[mt] = 0u;
      }
    }
    lsum += __shfl_xor(lsum, 16, 64);
    lsum += __shfl_xor(lsum, 32, 64);
    l_run = l_run * alpha + lsum;

#if HAVE_K16
    short4v pb[4];
#pragma unroll
    for (int mt = 0; mt < 4; ++mt) {
      uint2v uu;
      uu.x = u01[mt]; uu.y = u23[mt];
      pb[mt] = __builtin_bit_cast(short4v, uu);
    }
    __builtin_amdgcn_s_setprio(1);
#pragma unroll
    for (int et = 0; et < 4; ++et) {
      const short* vrow = &Vs[p][(et * 16 + col) * 64];
      floatx4 t0 = o[et];
#pragma unroll
      for (int r = 0; r < 4; ++r) t0[r] *= alpha;
#pragma unroll
      for (int mt = 0; mt < 4; ++mt) {
        if (mt <= mtmax) {
          int c = mt * 2 + (quad >> 1);
          short4v va = *(const short4v*)&vrow[((c ^ ksw) * 8) + (quad & 1) * 4];
          t0 = MFMAK16(va, pb[mt], t0);
        }
      }
      o[et] = t0;
    }
    __builtin_amdgcn_s_setprio(0);
#else
    short8 pf0, pf1;
    exchange4(u01, u23, srcA, srcB, hiq, pf0, pf1);
    __builtin_amdgcn_s_setprio(1);
#pragma unroll
    for (int et = 0; et < 4; ++et) {
      const short* vb = &Vs[p][(et * 16 + col) * 64];
      short8 va0 = *(const short8*)(vb + (quad ^ ksw) * 8);
      short8 va1 = *(const short8*)(vb + ((quad + 4) ^ ksw) * 8);
      floatx4 t0 = o[et];
#pragma unroll
      for (int r = 0; r < 4; ++r) t0[r] *= alpha;
      t0 = MFMA16(va0, pf0, t0);
      t0 = MFMA16(va1, pf1, t0);
      o[et] = t0;
    }
    __builtin_amdgcn_s_setprio(0);
#endif
    p ^= 1;
  }

  const int b = bh >> 4, h = bh & 15;
#if __has_builtin(__builtin_amdgcn_rcpf)
  const float invl = __builtin_amdgcn_rcpf(l_run);
#else
  const float invl = 1.f / l_run;
#endif
  unsigned short* zr = z + (((size_t)b * 2048 + qw0 + col) * 16 + h) * 64;
#pragma unroll
  for (int et = 0; et < 4; ++et) {
    ushort4 u;
    u.x = f2b(o[et][0] * invl); u.y = f2b(o[et][1] * invl);
    u.z = f2b(o[et][2] * invl); u.w = f2b(o[et][3] * invl);
    *(ushort4*)&zr[et * 16 + quad * 4] = u;
  }
}

// ---------------------------------------------------------------------------
extern "C" void kernel_launch(void* const* d_in, const int* in_sizes, int n_in,
                              void* d_out, int out_size, void* d_ws, size_t ws_size,
                              hipStream_t stream) {
  (void)in_sizes; (void)n_in; (void)out_size; (void)ws_size;
  const float* Xq = (const float*)d_in[0];
  const float* Xk = (const float*)d_in[1];
  const float* Xv = (const float*)d_in[2];
  const float* WQ = (const float*)d_in[3];
  const float* WK = (const float*)d_in[4];
  const float* WV = (const float*)d_in[5];
  const float* WO = (const float*)d_in[6];
  const float* bQ = (const float*)d_in[7];
  const float* bK = (const float*)d_in[8];
  const float* bV = (const float*)d_in[9];
  const float* bO = (const float*)d_in[10];
  float* out = (float*)d_out;

  unsigned short* xqb = (unsigned short*)d_ws;
  unsigned short* xkb = xqb + 4194304;
  unsigned short* xvb = xkb + 4194304;
  unsigned short* wqt = xvb + 4194304;
  unsigned short* wkt = wqt + 1048576;
  unsigned short* wvt = wkt + 1048576;
  unsigned short* wot = wvt + 1048576;
  unsigned short* qb = wot + 1048576;
  unsigned short* kb = qb + 4194304;
  unsigned short* vtb = kb + 4194304;
  unsigned short* zb = vtb + 4194304;

  convall<<<13312, 256, 0, stream>>>(Xq, Xk, Xv, WQ, WK, WV, WO, xqb, wqt, wot);

  const float qscale = 0.125f * 1.44269504088896f;  // 1/sqrt(64) * log2(e)
  gemm512<128, 128, 3><<<768, 512, 0, stream>>>(
      (const short*)xqb, (const short*)xkb, (const short*)xvb,
      (const short*)wqt, (const short*)wkt, (const short*)wvt, bQ, bK, bV, qb,
      kb, vtb, nullptr, qscale);

  attn<<<1024, 256, 0, stream>>>((const short*)qb, (const short*)kb,
                                 (const short*)vtb, zb);

  gemm512<64, 64, 1><<<1024, 512, 0, stream>>>(
      (const short*)zb, (const short*)zb, (const short*)zb, (const short*)wot,
      (const short*)wot, (const short*)wot, bO, bO, bO, nullptr, nullptr,
      nullptr, out, 1.0f);
}